// Round 1
// baseline (43.309 us; speedup 1.0000x reference)
//
#include <hip/hip_runtime.h>

// SparseDualFlow: fused elementwise momentum-prox recurrence over nnz values.
// flow=acc=0; repeat 20x:
//   acc_m = 0.9*acc
//   g     = 2*(flow - acc_m) - dd
//   acc   = acc_m + 0.01*g
//   flow  = relu(flow - acc)
// Each element is independent -> one memory-bound pass, recurrence in regs.

#define MOM   0.9f
#define STEP  0.01f
#define NITER 20

__global__ __launch_bounds__(256) void sdf_kernel(const float* __restrict__ dd,
                                                  float* __restrict__ out,
                                                  int n) {
    const int tid    = blockIdx.x * blockDim.x + threadIdx.x;
    const int stride = gridDim.x * blockDim.x;
    const int n4     = n >> 2;

    const float4* __restrict__ dd4  = reinterpret_cast<const float4*>(dd);
    float4* __restrict__       out4 = reinterpret_cast<float4*>(out);

    for (int i = tid; i < n4; i += stride) {
        const float4 dv = dd4[i];
        float d[4]    = {dv.x, dv.y, dv.z, dv.w};
        float flow[4] = {0.f, 0.f, 0.f, 0.f};
        float acc[4]  = {0.f, 0.f, 0.f, 0.f};

        #pragma unroll
        for (int it = 0; it < NITER; ++it) {
            #pragma unroll
            for (int j = 0; j < 4; ++j) {
                const float am = MOM * acc[j];
                const float fd = flow[j] - am;
                const float g  = 2.0f * fd - d[j];
                const float na = fmaf(STEP, g, am);   // acc_m + 0.01*g
                acc[j]  = na;
                flow[j] = fmaxf(flow[j] - na, 0.0f);  // relu prox step
            }
        }
        out4[i] = make_float4(flow[0], flow[1], flow[2], flow[3]);
    }

    // Scalar tail (n is 2^24 so normally empty; kept for safety).
    const int tail = n4 << 2;
    for (int i = tail + tid; i < n; i += stride) {
        const float d = dd[i];
        float flow = 0.f, acc = 0.f;
        #pragma unroll
        for (int it = 0; it < NITER; ++it) {
            const float am = MOM * acc;
            const float g  = 2.0f * (flow - am) - d;
            acc  = fmaf(STEP, g, am);
            flow = fmaxf(flow - acc, 0.0f);
        }
        out[i] = flow;
    }
}

extern "C" void kernel_launch(void* const* d_in, const int* in_sizes, int n_in,
                              void* d_out, int out_size, void* d_ws, size_t ws_size,
                              hipStream_t stream) {
    const float* dd = (const float*)d_in[0];
    float* out      = (float*)d_out;
    const int n     = in_sizes[0];

    const int block = 256;
    const int n4    = n >> 2;
    int grid = (n4 + block - 1) / block;
    if (grid > 2048) grid = 2048;   // grid-stride; ~8 float4 per thread at n=2^24
    if (grid < 1) grid = 1;

    sdf_kernel<<<grid, block, 0, stream>>>(dd, out, n);
}

// Round 2
// 25.300 us; speedup vs baseline: 1.7118x; 1.7118x over previous
//
#include <hip/hip_runtime.h>

// SparseDualFlow: the reference's 20-step momentum-prox recurrence is linear
// in the per-element state (flow0=acc0=0, all terms proportional to d):
//   acc'  = 0.9*acc + 0.01*(2*(flow - 0.9*acc) - d)
//   flow' = relu(flow - acc')
// For d > 0 the ReLU never clamps (coefficient trajectory f_t rises 0 -> ~0.45,
// pre-relu >= 0.01*d); for d <= 0 flow stays exactly 0 (pre-relu <= -0.01*|d|).
// Hence flow_20 = K * relu(d), K from a compile-time simulation of the
// recurrence at d=1. Kernel becomes a single memory-bound streaming pass.

constexpr float compute_K() {
    double a = 0.0, f = 0.0;
    for (int t = 0; t < 20; ++t) {
        const double am = 0.9 * a;
        const double g  = 2.0 * (f - am) - 1.0;   // gradient coeff of d
        a = am + 0.01 * g;
        f = f - a;                                 // relu never clamps for d>0
    }
    return (float)f;
}

__global__ __launch_bounds__(256) void sdf_kernel(const float* __restrict__ dd,
                                                  float* __restrict__ out,
                                                  int n) {
    constexpr float K = compute_K();

    const int tid    = blockIdx.x * blockDim.x + threadIdx.x;
    const int stride = gridDim.x * blockDim.x;
    const int n4     = n >> 2;

    const float4* __restrict__ dd4  = reinterpret_cast<const float4*>(dd);
    float4* __restrict__       out4 = reinterpret_cast<float4*>(out);

    for (int i = tid; i < n4; i += stride) {
        const float4 dv = dd4[i];
        float4 o;
        o.x = K * fmaxf(dv.x, 0.0f);
        o.y = K * fmaxf(dv.y, 0.0f);
        o.z = K * fmaxf(dv.z, 0.0f);
        o.w = K * fmaxf(dv.w, 0.0f);
        out4[i] = o;
    }

    // Scalar tail (n = 2^24 so normally empty; kept for safety).
    const int tail = n4 << 2;
    for (int i = tail + tid; i < n; i += stride) {
        out[i] = K * fmaxf(dd[i], 0.0f);
    }
}

extern "C" void kernel_launch(void* const* d_in, const int* in_sizes, int n_in,
                              void* d_out, int out_size, void* d_ws, size_t ws_size,
                              hipStream_t stream) {
    const float* dd = (const float*)d_in[0];
    float* out      = (float*)d_out;
    const int n     = in_sizes[0];

    const int block = 256;
    const int n4    = n >> 2;
    int grid = (n4 + block - 1) / block;
    if (grid > 2048) grid = 2048;   // grid-stride; ~8 float4 per thread at n=2^24
    if (grid < 1) grid = 1;

    sdf_kernel<<<grid, block, 0, stream>>>(dd, out, n);
}